// Round 6
// baseline (173.417 us; speedup 1.0000x reference)
//
#include <hip/hip_runtime.h>
#include <hip/hip_bf16.h>

#define NP 128
#define NPE 127

typedef short v8s __attribute__((ext_vector_type(8)));
typedef float v4f __attribute__((ext_vector_type(4)));

// LDS float offsets
#define L_HCJ 0      // 128 rows x 36 (j-half of layer-1)
#define L_HCI 4608   // 4 nodes x 32 (i-half incl bias)
#define L_GR  4736   // 4 waves x 128 x float4 {r0,r1,r2,rinv}
#define L_GD  6784   // 4 waves x 128 x float2 {d2,ds2}
#define L_TOT 7808   // 31232 B -> 5 blocks/CU

__device__ __forceinline__ float fast_rcp(float x){ return __builtin_amdgcn_rcpf(x); }
__device__ __forceinline__ float sigmoidf_(float x){ return fast_rcp(1.0f + __expf(-x)); }
__device__ __forceinline__ float siluf(float x){ return x * sigmoidf_(x); }
__device__ __forceinline__ float tanhf_fast(float x){
    return 1.0f - 2.0f * fast_rcp(1.0f + __expf(2.0f * x));
}
__device__ __forceinline__ short f2bf(float x){
    __hip_bfloat16 h = __float2bfloat16(x);
    return *reinterpret_cast<short*>(&h);
}
// pack bf16(a) (low) | bf16(b) (high): round-half-up + byte-perm, 3 VALU ops
__device__ __forceinline__ unsigned pkbf(float a, float b){
    const unsigned ua = __float_as_uint(a) + 0x8000u;
    const unsigned ub = __float_as_uint(b) + 0x8000u;
    return __builtin_amdgcn_perm(ub, ua, 0x07060302u);
}
union bfr { v8s v; unsigned u[4]; };

__global__ __launch_bounds__(256)
void eq_gnn_fused(const float* __restrict__ X, const float* __restrict__ Hin,
                  const float* __restrict__ DS,
                  const float* __restrict__ EW1, const float* __restrict__ EB1,
                  const float* __restrict__ EW2, const float* __restrict__ EB2,
                  const float* __restrict__ NW1, const float* __restrict__ NB1,
                  const float* __restrict__ NW2, const float* __restrict__ NB2,
                  const float* __restrict__ CW1, const float* __restrict__ CB1,
                  const float* __restrict__ CW2,
                  const float* __restrict__ AW,  const float* __restrict__ AB,
                  float* __restrict__ OUT)
{
    __shared__ float sm[L_TOT];
    const int tid  = threadIdx.x;
    const int lane = tid & 63;
    const int wid  = tid >> 6;
    const int m16  = lane & 15;
    const int q    = lane >> 4;
    const int bI   = blockIdx.x >> 5;    // batch
    const int grp  = blockIdx.x & 31;
    const int i    = grp * 4 + wid;      // this wave's node
    const int node = bI * 128 + i;

    // ---------- prologue A: HCj[row][o] = h[row]@W1[32:64] for all 128 batch rows ----------
    {
        v8s Aj0, Aj1;   // A = W1j^T : A[m=o][k] = W1[32+k][o]
        #pragma unroll
        for (int jj = 0; jj < 8; ++jj){
            Aj0[jj] = f2bf(EW1[(32 + q*8 + jj) * 32 + m16]);
            Aj1[jj] = f2bf(EW1[(32 + q*8 + jj) * 32 + 16 + m16]);
        }
        #pragma unroll
        for (int rr = 0; rr < 2; ++rr){
            const int row = (wid * 2 + rr) * 16 + m16;
            const float* hp = &Hin[(bI * 128 + row) * 32 + q * 8];
            const float4 h0 = *(const float4*)&hp[0];
            const float4 h1 = *(const float4*)&hp[4];
            bfr Bh;
            Bh.u[0] = pkbf(h0.x, h0.y); Bh.u[1] = pkbf(h0.z, h0.w);
            Bh.u[2] = pkbf(h1.x, h1.y); Bh.u[3] = pkbf(h1.z, h1.w);
            v4f d0 = {0.f,0.f,0.f,0.f}, d1 = {0.f,0.f,0.f,0.f};
            d0 = __builtin_amdgcn_mfma_f32_16x16x32_bf16(Aj0, Bh.v, d0, 0, 0, 0);
            d1 = __builtin_amdgcn_mfma_f32_16x16x32_bf16(Aj1, Bh.v, d1, 0, 0, 0);
            #pragma unroll
            for (int r = 0; r < 4; ++r){
                sm[L_HCJ + row * 36 + q*4 + r]      = d0[r];
                sm[L_HCJ + row * 36 + 16 + q*4 + r] = d1[r];
            }
        }
    }
    // ---------- prologue B: hci (i-half + bias) for the block's 4 nodes, fp32 ----------
    if (tid < 128){
        const int nl = tid >> 5, o = tid & 31;
        const float* hp = &Hin[(bI * 128 + grp * 4 + nl) * 32];
        float acc = EB1[o];
        #pragma unroll
        for (int k = 0; k < 32; ++k) acc = fmaf(hp[k], EW1[k * 32 + o], acc);
        sm[L_HCI + nl * 32 + o] = acc;
    }
    // ---------- prologue C: per-wave geometry, lane = edge (conflict-free strides) ----------
    float* sgr = &sm[L_GR + wid * 512];
    float* sgd = &sm[L_GD + wid * 256];
    const float xi0 = X[bI*384 + i*3 + 0];
    const float xi1 = X[bI*384 + i*3 + 1];
    const float xi2 = X[bI*384 + i*3 + 2];
    #pragma unroll
    for (int p = 0; p < 2; ++p){
        const int slot = lane + 64 * p;
        const int js = (slot < NPE) ? slot : 126;
        const int j = js + ((js >= i) ? 1 : 0);
        const float* xj = &X[bI*384 + j*3];
        const float r0 = xi0 - xj[0], r1 = xi1 - xj[1], r2 = xi2 - xj[2];
        const float d2 = fmaf(r0, r0, fmaf(r1, r1, fmaf(r2, r2, 1e-6f)));
        const float d  = sqrtf(d2);
        const float rinv = fast_rcp(d + 1.0f);
        const float dsv = DS[bI*16256 + i*127 + js];
        *(float4*)&sgr[slot*4] = make_float4(r0, r1, r2, rinv);
        *(float2*)&sgd[slot*2] = make_float2(d2, dsv * dsv);
    }
    __syncthreads();

    // ---------- persistent per-lane weight fragments (weights as A-operand) ----------
    v8s Aw20, Aw21, Ac0, Ac1;
    #pragma unroll
    for (int jj = 0; jj < 8; ++jj){
        Aw20[jj] = f2bf(EW2[(q*8 + jj) * 32 + m16]);        // A[m=f][k]=W2[k][f], half0
        Aw21[jj] = f2bf(EW2[(q*8 + jj) * 32 + 16 + m16]);   // half1
        const int tau = (jj < 4) ? (q*4 + jj) : (16 + q*4 + (jj - 4));
        Ac0[jj] = f2bf(CW1[tau * 32 + m16]);
        Ac1[jj] = f2bf(CW1[tau * 32 + 16 + m16]);
    }
    const float4 w64a = *(const float4*)&EW1[64*32 + q*8];
    const float4 w64b = *(const float4*)&EW1[64*32 + q*8 + 4];
    const float4 w65a = *(const float4*)&EW1[65*32 + q*8];
    const float4 w65b = *(const float4*)&EW1[65*32 + q*8 + 4];
    const float4 b2A = *(const float4*)&EB2[q*4];
    const float4 b2B = *(const float4*)&EB2[16 + q*4];
    const float4 cbA = *(const float4*)&CB1[q*4];
    const float4 cbB = *(const float4*)&CB1[16 + q*4];
    const float4 cwA = *(const float4*)&CW2[q*4];
    const float4 cwB = *(const float4*)&CW2[16 + q*4];
    const float4 awA = *(const float4*)&AW[q*4];
    const float4 awB = *(const float4*)&AW[16 + q*4];
    const float ab0 = AB[0];
    const float4 hci0 = *(const float4*)&sm[L_HCI + wid*32 + q*8];
    const float4 hci1 = *(const float4*)&sm[L_HCI + wid*32 + q*8 + 4];

    float ms[8];
    #pragma unroll
    for (int jj = 0; jj < 8; ++jj) ms[jj] = 0.f;
    float xc0 = 0.f, xc1 = 0.f, xc2 = 0.f;

    // ---------- edge loop: 8 tiles x 16 edges ----------
    #pragma unroll 1
    for (int tl = 0; tl < 8; ++tl){
        const int e = tl * 16 + m16;
        const float valid = (e < NPE) ? 1.f : 0.f;
        const int js = (e < NPE) ? e : 126;
        const int j = js + ((js >= i) ? 1 : 0);

        const float2 dd = *(const float2*)&sgd[e*2];                // d2, ds2
        const float4 hj0 = *(const float4*)&sm[L_HCJ + j*36 + q*8];
        const float4 hj1 = *(const float4*)&sm[L_HCJ + j*36 + q*8 + 4];

        // t1 as B-frag: slot (q,jj) = silu(hci+hcj+d2*w64+ds2*w65)[q*8+jj]
        const float t0 = siluf(fmaf(dd.x, w64a.x, fmaf(dd.y, w65a.x, hci0.x + hj0.x)));
        const float t1 = siluf(fmaf(dd.x, w64a.y, fmaf(dd.y, w65a.y, hci0.y + hj0.y)));
        const float t2 = siluf(fmaf(dd.x, w64a.z, fmaf(dd.y, w65a.z, hci0.z + hj0.z)));
        const float t3 = siluf(fmaf(dd.x, w64a.w, fmaf(dd.y, w65a.w, hci0.w + hj0.w)));
        const float t4 = siluf(fmaf(dd.x, w64b.x, fmaf(dd.y, w65b.x, hci1.x + hj1.x)));
        const float t5 = siluf(fmaf(dd.x, w64b.y, fmaf(dd.y, w65b.y, hci1.y + hj1.y)));
        const float t6 = siluf(fmaf(dd.x, w64b.z, fmaf(dd.y, w65b.z, hci1.z + hj1.z)));
        const float t7 = siluf(fmaf(dd.x, w64b.w, fmaf(dd.y, w65b.w, hci1.w + hj1.w)));
        bfr Bt;
        Bt.u[0] = pkbf(t0, t1); Bt.u[1] = pkbf(t2, t3);
        Bt.u[2] = pkbf(t4, t5); Bt.u[3] = pkbf(t6, t7);

        // layer 2: D[f][e] — lane holds edge e = m16, features q*4+r / 16+q*4+r
        v4f c0 = {b2A.x, b2A.y, b2A.z, b2A.w};
        v4f c1 = {b2B.x, b2B.y, b2B.z, b2B.w};
        c0 = __builtin_amdgcn_mfma_f32_16x16x32_bf16(Aw20, Bt.v, c0, 0, 0, 0);
        c1 = __builtin_amdgcn_mfma_f32_16x16x32_bf16(Aw21, Bt.v, c1, 0, 0, 0);
        const float s0 = siluf(c0[0]), s1 = siluf(c0[1]), s2 = siluf(c0[2]), s3 = siluf(c0[3]);
        const float s4 = siluf(c1[0]), s5 = siluf(c1[1]), s6 = siluf(c1[2]), s7 = siluf(c1[3]);

        // attention gate (partial over this lane's 8 features, then quad-sum)
        float lg = s0*awA.x + s1*awA.y + s2*awA.z + s3*awA.w
                 + s4*awB.x + s5*awB.y + s6*awB.z + s7*awB.w;
        lg += __shfl_xor(lg, 16, 64);
        lg += __shfl_xor(lg, 32, 64);
        const float att = sigmoidf_(lg + ab0) * valid;

        const float g0 = s0*att, g1 = s1*att, g2 = s2*att, g3 = s3*att;
        const float g4 = s4*att, g5 = s5*att, g6 = s6*att, g7 = s7*att;
        ms[0] += g0; ms[1] += g1; ms[2] += g2; ms[3] += g3;
        ms[4] += g4; ms[5] += g5; ms[6] += g6; ms[7] += g7;
        bfr Bm;
        Bm.u[0] = pkbf(g0, g1); Bm.u[1] = pkbf(g2, g3);
        Bm.u[2] = pkbf(g4, g5); Bm.u[3] = pkbf(g6, g7);

        // coord head: D2[o2][e]
        v4f e0 = {cbA.x, cbA.y, cbA.z, cbA.w};
        v4f e1 = {cbB.x, cbB.y, cbB.z, cbB.w};
        e0 = __builtin_amdgcn_mfma_f32_16x16x32_bf16(Ac0, Bm.v, e0, 0, 0, 0);
        e1 = __builtin_amdgcn_mfma_f32_16x16x32_bf16(Ac1, Bm.v, e1, 0, 0, 0);
        float tr = siluf(e0[0])*cwA.x + siluf(e0[1])*cwA.y + siluf(e0[2])*cwA.z + siluf(e0[3])*cwA.w
                 + siluf(e1[0])*cwB.x + siluf(e1[1])*cwB.y + siluf(e1[2])*cwB.z + siluf(e1[3])*cwB.w;
        tr += __shfl_xor(tr, 16, 64);
        tr += __shfl_xor(tr, 32, 64);

        const float4 rv = *(const float4*)&sgr[e*4];   // r0,r1,r2,rinv
        const float coef = tanhf_fast(tr) * rv.w * valid;
        xc0 = fmaf(rv.x, coef, xc0);
        xc1 = fmaf(rv.y, coef, xc1);
        xc2 = fmaf(rv.z, coef, xc2);
    }

    // ---------- reduce ms over the 16 edge-lanes within each quad ----------
    #pragma unroll
    for (int jj = 0; jj < 8; ++jj){
        float v = ms[jj];
        v += __shfl_xor(v, 1, 64); v += __shfl_xor(v, 2, 64);
        v += __shfl_xor(v, 4, 64); v += __shfl_xor(v, 8, 64);
        ms[jj] = v;
    }
    // ---------- reduce xc over all 64 lanes (each edge counted 4x) ----------
    {
        float v0 = xc0, v1 = xc1, v2 = xc2;
        #pragma unroll
        for (int s = 1; s < 64; s <<= 1){
            v0 += __shfl_xor(v0, s, 64);
            v1 += __shfl_xor(v1, s, 64);
            v2 += __shfl_xor(v2, s, 64);
        }
        xc0 = v0 * 0.25f; xc1 = v1 * 0.25f; xc2 = v2 * 0.25f;
    }

    if (lane < 3){
        const float xiv = (lane == 0) ? xi0 : ((lane == 1) ? xi1 : xi2);
        const float xcv = (lane == 0) ? xc0 : ((lane == 1) ? xc1 : xc2);
        OUT[bI*384 + i*3 + lane] = fmaf(xcv, 5.0f, xiv);
    }

    // ---------- stash ms (feature-ordered) into the now-free geometry LDS ----------
    if (m16 == 0){
        #pragma unroll
        for (int jj = 0; jj < 8; ++jj){
            const int tau = (jj < 4) ? (q*4 + jj) : (16 + q*4 + (jj - 4));
            sgr[tau] = ms[jj];
        }
    }

    // ---------- node MLP ----------
    const int o = lane & 31;
    const float* hp = &Hin[node * 32];
    float a1 = NB1[o];
    #pragma unroll
    for (int k = 0; k < 32; ++k) a1 = fmaf(hp[k], NW1[k * 32 + o], a1);
    #pragma unroll
    for (int k = 0; k < 32; ++k) a1 = fmaf(sgr[k], NW1[(32 + k) * 32 + o], a1);
    const float s1v = siluf(a1);
    float a2 = NB2[o];
    #pragma unroll
    for (int k = 0; k < 32; ++k) a2 = fmaf(__shfl(s1v, k, 64), NW2[k * 32 + o], a2);
    if (lane < 32)
        OUT[49152 + node * 32 + o] = hp[o] + a2;
}

extern "C" void kernel_launch(void* const* d_in, const int* in_sizes, int n_in,
                              void* d_out, int out_size, void* d_ws, size_t ws_size,
                              hipStream_t stream) {
    (void)in_sizes; (void)n_in; (void)out_size; (void)d_ws; (void)ws_size;
    eq_gnn_fused<<<dim3(4096), dim3(256), 0, stream>>>(
        (const float*)d_in[0],  (const float*)d_in[1],  (const float*)d_in[2],
        (const float*)d_in[3],  (const float*)d_in[4],  (const float*)d_in[5],  (const float*)d_in[6],
        (const float*)d_in[7],  (const float*)d_in[8],  (const float*)d_in[9],  (const float*)d_in[10],
        (const float*)d_in[11], (const float*)d_in[12], (const float*)d_in[13],
        (const float*)d_in[14], (const float*)d_in[15],
        (float*)d_out);
}

// Round 7
// 158.675 us; speedup vs baseline: 1.0929x; 1.0929x over previous
//
#include <hip/hip_runtime.h>
#include <hip/hip_bf16.h>

#define NPE 127

typedef short v8s __attribute__((ext_vector_type(8)));
typedef float v4f __attribute__((ext_vector_type(4)));
typedef float v2f __attribute__((ext_vector_type(2)));

// LDS float offsets (512-thread block = 8 waves = 8 nodes; HCJ shared per batch)
#define L_HCJ 0       // 128 rows x 36
#define L_HCI 4608    // 8 nodes x 32
#define L_GR  4864    // 8 waves x 128 x float4 {r0,r1,r2,rinv}
#define L_GD  8960    // 8 waves x 128 x float2 {d2,ds2}
#define L_TOT 11008   // 44032 B -> 3 blocks/CU (24 waves)

__device__ __forceinline__ float fast_rcp(float x){ return __builtin_amdgcn_rcpf(x); }
__device__ __forceinline__ float exp2_fast(float x){
#if __has_builtin(__builtin_amdgcn_exp2f)
    return __builtin_amdgcn_exp2f(x);
#else
    return exp2f(x);
#endif
}
#define LOG2E 1.44269504f
__device__ __forceinline__ float sigmoidf_(float x){
    return fast_rcp(1.0f + exp2_fast(-LOG2E * x));
}
__device__ __forceinline__ float tanhf_fast(float x){
    return fmaf(-2.0f, fast_rcp(1.0f + exp2_fast(2.0f * LOG2E * x)), 1.0f);
}
__device__ __forceinline__ v2f splat2(float v){ v2f r; r.x = v; r.y = v; return r; }
// packed-f32 silu: fma/add/mul lower to v_pk_*; exp/rcp stay scalar (per-element)
__device__ __forceinline__ v2f silu2(v2f x){
    v2f t = x * splat2(-LOG2E);
    v2f e; e.x = exp2_fast(t.x); e.y = exp2_fast(t.y);
    v2f d = e + splat2(1.0f);
    v2f r; r.x = fast_rcp(d.x); r.y = fast_rcp(d.y);
    return x * r;
}
__device__ __forceinline__ short f2bf(float x){
    __hip_bfloat16 h = __float2bfloat16(x);
    return *reinterpret_cast<short*>(&h);
}
union f4u { float4 f4; v2f v2[2]; float f[4]; };

__global__ __launch_bounds__(512)
void eq_gnn_fused(const float* __restrict__ X, const float* __restrict__ Hin,
                  const float* __restrict__ DS,
                  const float* __restrict__ EW1, const float* __restrict__ EB1,
                  const float* __restrict__ EW2, const float* __restrict__ EB2,
                  const float* __restrict__ NW1, const float* __restrict__ NB1,
                  const float* __restrict__ NW2, const float* __restrict__ NB2,
                  const float* __restrict__ CW1, const float* __restrict__ CB1,
                  const float* __restrict__ CW2,
                  const float* __restrict__ AW,  const float* __restrict__ AB,
                  float* __restrict__ OUT)
{
    __shared__ float sm[L_TOT];
    const int tid  = threadIdx.x;
    const int lane = tid & 63;
    const int wid  = tid >> 6;           // 0..7
    const int m16  = lane & 15;
    const int q    = lane >> 4;
    const int bI   = blockIdx.x >> 4;    // batch
    const int grp  = blockIdx.x & 15;
    const int i    = grp * 8 + wid;      // this wave's node
    const int node = bI * 128 + i;

    // ---------- prologue A: HCj[row][o] = h[row]@W1[32:64]; each wave does 16 rows ----------
    {
        v8s Aj0, Aj1;   // A = W1j^T : A[m=o][k] = W1[32+k][o]
        #pragma unroll
        for (int jj = 0; jj < 8; ++jj){
            Aj0[jj] = f2bf(EW1[(32 + q*8 + jj) * 32 + m16]);
            Aj1[jj] = f2bf(EW1[(32 + q*8 + jj) * 32 + 16 + m16]);
        }
        const int row = wid * 16 + m16;
        const float* hp = &Hin[(bI * 128 + row) * 32 + q * 8];
        const float4 h0 = *(const float4*)&hp[0];
        const float4 h1 = *(const float4*)&hp[4];
        v8s Bh;
        Bh[0]=f2bf(h0.x); Bh[1]=f2bf(h0.y); Bh[2]=f2bf(h0.z); Bh[3]=f2bf(h0.w);
        Bh[4]=f2bf(h1.x); Bh[5]=f2bf(h1.y); Bh[6]=f2bf(h1.z); Bh[7]=f2bf(h1.w);
        v4f d0 = {0.f,0.f,0.f,0.f}, d1 = {0.f,0.f,0.f,0.f};
        d0 = __builtin_amdgcn_mfma_f32_16x16x32_bf16(Aj0, Bh, d0, 0, 0, 0);
        d1 = __builtin_amdgcn_mfma_f32_16x16x32_bf16(Aj1, Bh, d1, 0, 0, 0);
        #pragma unroll
        for (int r = 0; r < 4; ++r){
            sm[L_HCJ + row * 36 + q*4 + r]      = d0[r];
            sm[L_HCJ + row * 36 + 16 + q*4 + r] = d1[r];
        }
    }
    // ---------- prologue B: hci (i-half + bias) for the block's 8 nodes ----------
    if (tid < 256){
        const int nl = tid >> 5, o = tid & 31;
        const float* hp = &Hin[(bI * 128 + grp * 8 + nl) * 32];
        float acc = EB1[o];
        #pragma unroll
        for (int k = 0; k < 32; ++k) acc = fmaf(hp[k], EW1[k * 32 + o], acc);
        sm[L_HCI + nl * 32 + o] = acc;
    }
    // ---------- prologue C: per-wave geometry, lane = edge ----------
    float* sgr = &sm[L_GR + wid * 512];
    float* sgd = &sm[L_GD + wid * 256];
    const float xi0 = X[bI*384 + i*3 + 0];
    const float xi1 = X[bI*384 + i*3 + 1];
    const float xi2 = X[bI*384 + i*3 + 2];
    #pragma unroll
    for (int p = 0; p < 2; ++p){
        const int slot = lane + 64 * p;
        const int js = (slot < NPE) ? slot : 126;
        const int j = js + ((js >= i) ? 1 : 0);
        const float* xj = &X[bI*384 + j*3];
        const float r0 = xi0 - xj[0], r1 = xi1 - xj[1], r2 = xi2 - xj[2];
        const float d2 = fmaf(r0, r0, fmaf(r1, r1, fmaf(r2, r2, 1e-6f)));
        const float d  = sqrtf(d2);
        const float rinv = fast_rcp(d + 1.0f);
        const float dsv = DS[bI*16256 + i*127 + js];
        *(float4*)&sgr[slot*4] = make_float4(r0, r1, r2, rinv);
        *(float2*)&sgd[slot*2] = make_float2(d2, dsv * dsv);
    }
    __syncthreads();

    // ---------- persistent per-lane weight fragments ----------
    v8s Aw20, Aw21, Ac0, Ac1;
    #pragma unroll
    for (int jj = 0; jj < 8; ++jj){
        Aw20[jj] = f2bf(EW2[(q*8 + jj) * 32 + m16]);
        Aw21[jj] = f2bf(EW2[(q*8 + jj) * 32 + 16 + m16]);
        const int tau = (jj < 4) ? (q*4 + jj) : (16 + q*4 + (jj - 4));
        Ac0[jj] = f2bf(CW1[tau * 32 + m16]);
        Ac1[jj] = f2bf(CW1[tau * 32 + 16 + m16]);
    }
    f4u w64a, w64b, w65a, w65b, hcia, hcib, awa, awb, cwa, cwb;
    w64a.f4 = *(const float4*)&EW1[64*32 + q*8];
    w64b.f4 = *(const float4*)&EW1[64*32 + q*8 + 4];
    w65a.f4 = *(const float4*)&EW1[65*32 + q*8];
    w65b.f4 = *(const float4*)&EW1[65*32 + q*8 + 4];
    hcia.f4 = *(const float4*)&sm[L_HCI + wid*32 + q*8];
    hcib.f4 = *(const float4*)&sm[L_HCI + wid*32 + q*8 + 4];
    awa.f4  = *(const float4*)&AW[q*4];        // C-space: features q*4+r
    awb.f4  = *(const float4*)&AW[16 + q*4];
    cwa.f4  = *(const float4*)&CW2[q*4];
    cwb.f4  = *(const float4*)&CW2[16 + q*4];
    const float4 b2A = *(const float4*)&EB2[q*4];
    const float4 b2B = *(const float4*)&EB2[16 + q*4];
    const float4 cbA = *(const float4*)&CB1[q*4];
    const float4 cbB = *(const float4*)&CB1[16 + q*4];
    const float ab0 = AB[0];

    v2f ms2[4];
    #pragma unroll
    for (int g = 0; g < 4; ++g) ms2[g] = splat2(0.f);
    float xc0 = 0.f, xc1 = 0.f, xc2 = 0.f;

    // ---------- edge loop: 8 tiles x 16 edges ----------
    #pragma unroll 1
    for (int tl = 0; tl < 8; ++tl){
        const int e = tl * 16 + m16;
        const float valid = (e < NPE) ? 1.f : 0.f;
        const int js = (e < NPE) ? e : 126;
        const int j = js + ((js >= i) ? 1 : 0);

        const float2 dd = *(const float2*)&sgd[e*2];
        f4u hjA, hjB;
        hjA.f4 = *(const float4*)&sm[L_HCJ + j*36 + q*8];
        hjB.f4 = *(const float4*)&sm[L_HCJ + j*36 + q*8 + 4];
        const v2f d2s  = splat2(dd.x);
        const v2f ds2s = splat2(dd.y);

        // t1 (B-frag slots k=q*8+jj), packed-f32 chains
        v2f t01, t23, t45, t67;
        {
            v2f z;
            z = hcia.v2[0] + hjA.v2[0];
            z = __builtin_elementwise_fma(d2s, w64a.v2[0], z);
            z = __builtin_elementwise_fma(ds2s, w65a.v2[0], z);
            t01 = silu2(z);
            z = hcia.v2[1] + hjA.v2[1];
            z = __builtin_elementwise_fma(d2s, w64a.v2[1], z);
            z = __builtin_elementwise_fma(ds2s, w65a.v2[1], z);
            t23 = silu2(z);
            z = hcib.v2[0] + hjB.v2[0];
            z = __builtin_elementwise_fma(d2s, w64b.v2[0], z);
            z = __builtin_elementwise_fma(ds2s, w65b.v2[0], z);
            t45 = silu2(z);
            z = hcib.v2[1] + hjB.v2[1];
            z = __builtin_elementwise_fma(d2s, w64b.v2[1], z);
            z = __builtin_elementwise_fma(ds2s, w65b.v2[1], z);
            t67 = silu2(z);
        }
        v8s Bt;
        Bt[0]=f2bf(t01.x); Bt[1]=f2bf(t01.y); Bt[2]=f2bf(t23.x); Bt[3]=f2bf(t23.y);
        Bt[4]=f2bf(t45.x); Bt[5]=f2bf(t45.y); Bt[6]=f2bf(t67.x); Bt[7]=f2bf(t67.y);

        // layer 2: D[f][e]
        v4f c0 = {b2A.x, b2A.y, b2A.z, b2A.w};
        v4f c1 = {b2B.x, b2B.y, b2B.z, b2B.w};
        c0 = __builtin_amdgcn_mfma_f32_16x16x32_bf16(Aw20, Bt, c0, 0, 0, 0);
        c1 = __builtin_amdgcn_mfma_f32_16x16x32_bf16(Aw21, Bt, c1, 0, 0, 0);
        v2f sa, sb, sc, sd;
        { v2f z; z.x=c0[0]; z.y=c0[1]; sa = silu2(z); }
        { v2f z; z.x=c0[2]; z.y=c0[3]; sb = silu2(z); }
        { v2f z; z.x=c1[0]; z.y=c1[1]; sc = silu2(z); }
        { v2f z; z.x=c1[2]; z.y=c1[3]; sd = silu2(z); }

        // attention gate (C-space ordering)
        v2f lgv = sa * awa.v2[0];
        lgv = __builtin_elementwise_fma(sb, awa.v2[1], lgv);
        lgv = __builtin_elementwise_fma(sc, awb.v2[0], lgv);
        lgv = __builtin_elementwise_fma(sd, awb.v2[1], lgv);
        float lg = lgv.x + lgv.y;
        lg += __shfl_xor(lg, 16, 64);
        lg += __shfl_xor(lg, 32, 64);
        const float att = sigmoidf_(lg + ab0) * valid;
        const v2f atts = splat2(att);

        const v2f g0 = sa * atts, g1 = sb * atts, g2 = sc * atts, g3 = sd * atts;
        ms2[0] += g0; ms2[1] += g1; ms2[2] += g2; ms2[3] += g3;
        v8s Bm;
        Bm[0]=f2bf(g0.x); Bm[1]=f2bf(g0.y); Bm[2]=f2bf(g1.x); Bm[3]=f2bf(g1.y);
        Bm[4]=f2bf(g2.x); Bm[5]=f2bf(g2.y); Bm[6]=f2bf(g3.x); Bm[7]=f2bf(g3.y);

        // coord head
        v4f e0 = {cbA.x, cbA.y, cbA.z, cbA.w};
        v4f e1 = {cbB.x, cbB.y, cbB.z, cbB.w};
        e0 = __builtin_amdgcn_mfma_f32_16x16x32_bf16(Ac0, Bm, e0, 0, 0, 0);
        e1 = __builtin_amdgcn_mfma_f32_16x16x32_bf16(Ac1, Bm, e1, 0, 0, 0);
        v2f ca, cb, cc, cd;
        { v2f z; z.x=e0[0]; z.y=e0[1]; ca = silu2(z); }
        { v2f z; z.x=e0[2]; z.y=e0[3]; cb = silu2(z); }
        { v2f z; z.x=e1[0]; z.y=e1[1]; cc = silu2(z); }
        { v2f z; z.x=e1[2]; z.y=e1[3]; cd = silu2(z); }
        v2f trv = ca * cwa.v2[0];
        trv = __builtin_elementwise_fma(cb, cwa.v2[1], trv);
        trv = __builtin_elementwise_fma(cc, cwb.v2[0], trv);
        trv = __builtin_elementwise_fma(cd, cwb.v2[1], trv);
        float tr = trv.x + trv.y;
        tr += __shfl_xor(tr, 16, 64);
        tr += __shfl_xor(tr, 32, 64);

        const float4 rv = *(const float4*)&sgr[e*4];   // r0,r1,r2,rinv
        const float coef = tanhf_fast(tr) * rv.w * valid;
        xc0 = fmaf(rv.x, coef, xc0);
        xc1 = fmaf(rv.y, coef, xc1);
        xc2 = fmaf(rv.z, coef, xc2);
    }

    // ---------- reduce ms over the 16 edge-lanes within each quad ----------
    float msv[8] = {ms2[0].x, ms2[0].y, ms2[1].x, ms2[1].y,
                    ms2[2].x, ms2[2].y, ms2[3].x, ms2[3].y};
    #pragma unroll
    for (int jj = 0; jj < 8; ++jj){
        float v = msv[jj];
        v += __shfl_xor(v, 1, 64); v += __shfl_xor(v, 2, 64);
        v += __shfl_xor(v, 4, 64); v += __shfl_xor(v, 8, 64);
        msv[jj] = v;
    }
    // ---------- reduce xc over all 64 lanes (each edge counted 4x) ----------
    {
        float v0 = xc0, v1 = xc1, v2 = xc2;
        #pragma unroll
        for (int s = 1; s < 64; s <<= 1){
            v0 += __shfl_xor(v0, s, 64);
            v1 += __shfl_xor(v1, s, 64);
            v2 += __shfl_xor(v2, s, 64);
        }
        xc0 = v0 * 0.25f; xc1 = v1 * 0.25f; xc2 = v2 * 0.25f;
    }

    if (lane < 3){
        const float xiv = (lane == 0) ? xi0 : ((lane == 1) ? xi1 : xi2);
        const float xcv = (lane == 0) ? xc0 : ((lane == 1) ? xc1 : xc2);
        OUT[bI*384 + i*3 + lane] = fmaf(xcv, 5.0f, xiv);
    }

    // ---------- stash ms (feature-ordered) into now-free geometry LDS ----------
    if (m16 == 0){
        #pragma unroll
        for (int jj = 0; jj < 8; ++jj){
            const int tau = (jj < 4) ? (q*4 + jj) : (16 + q*4 + (jj - 4));
            sgr[tau] = msv[jj];
        }
    }

    // ---------- node MLP ----------
    const int o = lane & 31;
    const float* hp = &Hin[node * 32];
    float a1 = NB1[o];
    #pragma unroll
    for (int k = 0; k < 32; ++k) a1 = fmaf(hp[k], NW1[k * 32 + o], a1);
    #pragma unroll
    for (int k = 0; k < 32; ++k) a1 = fmaf(sgr[k], NW1[(32 + k) * 32 + o], a1);
    const float s1v = a1 * sigmoidf_(a1);
    float a2 = NB2[o];
    #pragma unroll
    for (int k = 0; k < 32; ++k) a2 = fmaf(__shfl(s1v, k, 64), NW2[k * 32 + o], a2);
    if (lane < 32)
        OUT[49152 + node * 32 + o] = hp[o] + a2;
}

extern "C" void kernel_launch(void* const* d_in, const int* in_sizes, int n_in,
                              void* d_out, int out_size, void* d_ws, size_t ws_size,
                              hipStream_t stream) {
    (void)in_sizes; (void)n_in; (void)out_size; (void)d_ws; (void)ws_size;
    eq_gnn_fused<<<dim3(2048), dim3(512), 0, stream>>>(
        (const float*)d_in[0],  (const float*)d_in[1],  (const float*)d_in[2],
        (const float*)d_in[3],  (const float*)d_in[4],  (const float*)d_in[5],  (const float*)d_in[6],
        (const float*)d_in[7],  (const float*)d_in[8],  (const float*)d_in[9],  (const float*)d_in[10],
        (const float*)d_in[11], (const float*)d_in[12], (const float*)d_in[13],
        (const float*)d_in[14], (const float*)d_in[15],
        (float*)d_out);
}